// Round 1
// baseline (643.529 us; speedup 1.0000x reference)
//
#include <hip/hip_runtime.h>

#define E_      8
#define D_      1024
#define H_      2048
#define TOKENS  8192
#define RROWS   16384            // routed rows total (= TOKENS * TOP_K), exact
#define HPAD_ROWS (RROWS + 128)  // pad so GEMM2 A-staging over-read stays in bounds

using bf16x8 = __attribute__((ext_vector_type(8))) __bf16;
using f32x4  = __attribute__((ext_vector_type(4))) float;

__device__ __forceinline__ unsigned short f2bf(float f) {
  unsigned u = __builtin_bit_cast(unsigned, f);
  u += 0x7fffu + ((u >> 16) & 1u);   // RNE
  return (unsigned short)(u >> 16);
}

// async global->LDS, 16B per lane; LDS dest is wave-uniform base + lane*16
#define GLDS16(g, l) __builtin_amdgcn_global_load_lds( \
    (const __attribute__((address_space(1))) unsigned int*)(g), \
    (__attribute__((address_space(3))) unsigned int*)(l), 16, 0, 0)

// ---------------- prologue kernels ----------------

__global__ void cvt_bf16_kernel(const float* __restrict__ s,
                                unsigned short* __restrict__ d, int n4) {
  int i = blockIdx.x * blockDim.x + threadIdx.x;
  int stride = gridDim.x * blockDim.x;
  for (; i < n4; i += stride) {
    float4 v = reinterpret_cast<const float4*>(s)[i];
    ushort4 o = make_ushort4(f2bf(v.x), f2bf(v.y), f2bf(v.z), f2bf(v.w));
    reinterpret_cast<ushort4*>(d)[i] = o;
  }
}

// src: [E][R][C] fp32  ->  dst: [E][C][R] bf16
__global__ void transpose_cvt_kernel(const float* __restrict__ src,
                                     unsigned short* __restrict__ dst,
                                     int R, int C) {
  int tilesC = C >> 6, tilesR = R >> 6;
  int per = tilesR * tilesC;
  int b = blockIdx.x;
  int e = b / per, rem = b % per;
  int rb = rem / tilesC, cb = rem % tilesC;
  __shared__ float tile[64][65];
  const float* s = src + (size_t)e * R * C;
  unsigned short* d = dst + (size_t)e * R * C;
  int r0 = rb << 6, c0 = cb << 6;
#pragma unroll
  for (int i = 0; i < 16; i++) {
    int idx = threadIdx.x + i * 256;
    int lr = idx >> 6, lc = idx & 63;
    tile[lr][lc] = s[(size_t)(r0 + lr) * C + (c0 + lc)];
  }
  __syncthreads();
#pragma unroll
  for (int i = 0; i < 16; i++) {
    int idx = threadIdx.x + i * 256;
    int lr = idx >> 6, lc = idx & 63;
    d[(size_t)(c0 + lr) * R + (r0 + lc)] = f2bf(tile[lc][lr]);
  }
}

__global__ void gating_kernel(const float* __restrict__ x, const float* __restrict__ gate,
                              int* __restrict__ sel, float* __restrict__ wsel,
                              int* __restrict__ cnt) {
  int lane = threadIdx.x & 63, wid = threadIdx.x >> 6;
  int t = (blockIdx.x << 2) + wid;          // one wave per token
  const float* xr = x + (size_t)t * D_;
  float acc[8];
#pragma unroll
  for (int e = 0; e < 8; e++) acc[e] = 0.f;
  for (int i = 0; i < D_ / 64; i++) {
    int dd = (i << 6) + lane;
    float xv = xr[dd];
    const float4* g4 = reinterpret_cast<const float4*>(gate + dd * 8);
    float4 ga = g4[0], gb = g4[1];
    acc[0] += xv * ga.x; acc[1] += xv * ga.y; acc[2] += xv * ga.z; acc[3] += xv * ga.w;
    acc[4] += xv * gb.x; acc[5] += xv * gb.y; acc[6] += xv * gb.z; acc[7] += xv * gb.w;
  }
#pragma unroll
  for (int e = 0; e < 8; e++) {
#pragma unroll
    for (int off = 32; off; off >>= 1) acc[e] += __shfl_xor(acc[e], off);
  }
  if (lane == 0) {
    int i0 = 0; float v0 = acc[0];
#pragma unroll
    for (int e = 1; e < 8; e++) if (acc[e] > v0) { v0 = acc[e]; i0 = e; }
    int i1 = -1; float v1 = -3.4e38f;
#pragma unroll
    for (int e = 0; e < 8; e++) if (e != i0 && acc[e] > v1) { v1 = acc[e]; i1 = e; }
    // top-2-of-softmax renormalized: w0 = p0/(p0+p1) with p = exp(l - l_max)
    float p1 = expf(v1 - v0);
    float inv = 1.f / (1.f + p1);
    sel[t * 2] = i0; sel[t * 2 + 1] = i1;
    wsel[t * 2] = inv; wsel[t * 2 + 1] = p1 * inv;
    atomicAdd(&cnt[i0], 1);
    atomicAdd(&cnt[i1], 1);
  }
}

__global__ void scan_kernel(const int* __restrict__ cnt, int* __restrict__ off,
                            int* __restrict__ cursor) {
  if (threadIdx.x == 0) {
    int a = 0;
    for (int e = 0; e < 8; e++) { off[e] = a; cursor[e] = a; a += cnt[e]; }
  }
}

__global__ void scatter_kernel(const int* __restrict__ sel, const float* __restrict__ wsel,
                               int* __restrict__ cursor, int* __restrict__ tok_id,
                               float* __restrict__ rw) {
  int t = blockIdx.x * blockDim.x + threadIdx.x;
  if (t >= TOKENS) return;
  int e0 = sel[t * 2], e1 = sel[t * 2 + 1];
  int p0 = atomicAdd(&cursor[e0], 1);
  tok_id[p0] = t; rw[p0] = wsel[t * 2];
  int p1 = atomicAdd(&cursor[e1], 1);
  tok_id[p1] = t; rw[p1] = wsel[t * 2 + 1];
}

// ---------------- grouped GEMMs ----------------
// 128x128 tile, BK=64, 4 waves (2x2), 16x16x32 bf16 MFMA.
// LDS layout: [128 rows][64 k] bf16, XOR-swizzled 16B chunks (chunk^(row&7)),
// swizzle applied on the per-lane GLOBAL address (LDS dest stays linear).

__global__ __launch_bounds__(256) void gemm1_kernel(
    const unsigned short* __restrict__ xb,    // [TOKENS][D_] bf16
    const unsigned short* __restrict__ w1t,   // [E][H][D] bf16 (k=d contiguous)
    const float* __restrict__ b1,             // [E][H]
    unsigned short* __restrict__ hbuf,        // [HPAD_ROWS][H_] bf16
    const int* __restrict__ tok_id,
    const int* __restrict__ cnt, const int* __restrict__ off) {
  const int bid = blockIdx.x;
  const int e  = bid >> 10;          // 64 rb * 16 cb
  const int rb = (bid >> 4) & 63;
  const int cb = bid & 15;
  const int rows = cnt[e];
  const int m0 = rb << 7;
  if (m0 >= rows) return;
  const int base = off[e];
  const int tid = threadIdx.x, lane = tid & 63, wid = tid >> 6;
  const int wr = wid >> 1, wc = wid & 1;

  __shared__ __align__(16) unsigned short Asm[128 * 64];
  __shared__ __align__(16) unsigned short Bsm[128 * 64];
  __shared__ int toksm[128];

  if (tid < 128) {
    int r = m0 + tid;
    if (r >= rows) r = rows - 1;     // clamp: garbage rows computed, never stored
    toksm[tid] = tok_id[base + r];
  }
  __syncthreads();

  const int c8 = lane & 7, r8 = lane >> 3;
  const size_t swz = (size_t)((c8 ^ r8) << 4);
  size_t gA[4], gB[4];
  const int n0 = cb << 7;
#pragma unroll
  for (int i = 0; i < 4; i++) {
    int r = ((wid << 2) + i) << 3;   // 8-row group base
    gA[i] = (size_t)toksm[r + r8] * (D_ * 2) + swz;
    gB[i] = (size_t)(n0 + r + r8) * (D_ * 2) + swz;
  }
  const char* Ab = (const char*)xb;
  const char* Bb = (const char*)w1t + (size_t)e * H_ * D_ * 2;

  f32x4 acc[4][4] = {};

  for (int k0 = 0; k0 < D_; k0 += 64) {
    __syncthreads();
#pragma unroll
    for (int i = 0; i < 4; i++)
      GLDS16(Ab + gA[i] + k0 * 2, &Asm[((wid << 2) + i) << 9]);
#pragma unroll
    for (int i = 0; i < 4; i++)
      GLDS16(Bb + gB[i] + k0 * 2, &Bsm[((wid << 2) + i) << 9]);
    asm volatile("s_waitcnt vmcnt(0)" ::: "memory");
    __syncthreads();
#pragma unroll
    for (int kk = 0; kk < 2; kk++) {
      const int cby = (((kk << 2) + (lane >> 4)) ^ (lane & 7)) << 4;
      bf16x8 a[4], b[4];
      const char* Ap = (const char*)Asm + ((wr << 6) + (lane & 15)) * 128 + cby;
      const char* Bp = (const char*)Bsm + ((wc << 6) + (lane & 15)) * 128 + cby;
#pragma unroll
      for (int mi = 0; mi < 4; mi++) a[mi] = *(const bf16x8*)(Ap + mi * 2048);
#pragma unroll
      for (int ni = 0; ni < 4; ni++) b[ni] = *(const bf16x8*)(Bp + ni * 2048);
#pragma unroll
      for (int mi = 0; mi < 4; mi++)
#pragma unroll
        for (int ni = 0; ni < 4; ni++)
          acc[mi][ni] = __builtin_amdgcn_mfma_f32_16x16x32_bf16(a[mi], b[ni], acc[mi][ni], 0, 0, 0);
    }
  }

  const int rcnt = rows - m0;
  const float* b1e = b1 + e * H_;
#pragma unroll
  for (int mi = 0; mi < 4; mi++) {
#pragma unroll
    for (int q = 0; q < 4; q++) {
      int rl = (wr << 6) + (mi << 4) + ((lane >> 4) << 2) + q;
      if (rl < rcnt) {
        unsigned short* hrow = hbuf + (size_t)(base + m0 + rl) * H_;
#pragma unroll
        for (int ni = 0; ni < 4; ni++) {
          int ncol = n0 + (wc << 6) + (ni << 4) + (lane & 15);
          float v = acc[mi][ni][q] + b1e[ncol];
          hrow[ncol] = f2bf(fmaxf(v, 0.f));
        }
      }
    }
  }
}

__global__ __launch_bounds__(256) void gemm2_kernel(
    const unsigned short* __restrict__ hbuf,  // [HPAD_ROWS][H_] bf16
    const unsigned short* __restrict__ w2t,   // [E][D][H] bf16 (k=h contiguous)
    const float* __restrict__ b2,             // [E][D]
    float* __restrict__ out,                  // [TOKENS][D_] fp32 (zeroed)
    const int* __restrict__ tok_id, const float* __restrict__ rw,
    const int* __restrict__ cnt, const int* __restrict__ off) {
  const int bid = blockIdx.x;
  const int e  = bid >> 9;           // 64 rb * 8 cb
  const int rb = (bid >> 3) & 63;
  const int cb = bid & 7;
  const int rows = cnt[e];
  const int m0 = rb << 7;
  if (m0 >= rows) return;
  const int base = off[e];
  const int tid = threadIdx.x, lane = tid & 63, wid = tid >> 6;
  const int wr = wid >> 1, wc = wid & 1;

  __shared__ __align__(16) unsigned short Asm[128 * 64];
  __shared__ __align__(16) unsigned short Bsm[128 * 64];

  const int c8 = lane & 7, r8 = lane >> 3;
  const size_t swz = (size_t)((c8 ^ r8) << 4);
  size_t gA[4], gB[4];
  const int n0 = cb << 7;
#pragma unroll
  for (int i = 0; i < 4; i++) {
    int r = ((wid << 2) + i) << 3;
    gA[i] = (size_t)(base + m0 + r + r8) * (H_ * 2) + swz;  // contiguous routed rows
    gB[i] = (size_t)(n0 + r + r8) * (H_ * 2) + swz;
  }
  const char* Ab = (const char*)hbuf;
  const char* Bb = (const char*)w2t + (size_t)e * D_ * H_ * 2;

  f32x4 acc[4][4] = {};

  for (int k0 = 0; k0 < H_; k0 += 64) {
    __syncthreads();
#pragma unroll
    for (int i = 0; i < 4; i++)
      GLDS16(Ab + gA[i] + k0 * 2, &Asm[((wid << 2) + i) << 9]);
#pragma unroll
    for (int i = 0; i < 4; i++)
      GLDS16(Bb + gB[i] + k0 * 2, &Bsm[((wid << 2) + i) << 9]);
    asm volatile("s_waitcnt vmcnt(0)" ::: "memory");
    __syncthreads();
#pragma unroll
    for (int kk = 0; kk < 2; kk++) {
      const int cby = (((kk << 2) + (lane >> 4)) ^ (lane & 7)) << 4;
      bf16x8 a[4], b[4];
      const char* Ap = (const char*)Asm + ((wr << 6) + (lane & 15)) * 128 + cby;
      const char* Bp = (const char*)Bsm + ((wc << 6) + (lane & 15)) * 128 + cby;
#pragma unroll
      for (int mi = 0; mi < 4; mi++) a[mi] = *(const bf16x8*)(Ap + mi * 2048);
#pragma unroll
      for (int ni = 0; ni < 4; ni++) b[ni] = *(const bf16x8*)(Bp + ni * 2048);
#pragma unroll
      for (int mi = 0; mi < 4; mi++)
#pragma unroll
        for (int ni = 0; ni < 4; ni++)
          acc[mi][ni] = __builtin_amdgcn_mfma_f32_16x16x32_bf16(a[mi], b[ni], acc[mi][ni], 0, 0, 0);
    }
  }

  const int rcnt = rows - m0;
  const float* b2e = b2 + e * D_;
#pragma unroll
  for (int mi = 0; mi < 4; mi++) {
#pragma unroll
    for (int q = 0; q < 4; q++) {
      int rl = (wr << 6) + (mi << 4) + ((lane >> 4) << 2) + q;
      if (rl < rcnt) {
        int R = base + m0 + rl;
        float w = rw[R];
        int t = tok_id[R];
        float* orow = out + (size_t)t * D_;
#pragma unroll
        for (int ni = 0; ni < 4; ni++) {
          int ncol = n0 + (wc << 6) + (ni << 4) + (lane & 15);
          atomicAdd(&orow[ncol], w * (acc[mi][ni][q] + b2e[ncol]));
        }
      }
    }
  }
}

// ---------------- launcher ----------------

extern "C" void kernel_launch(void* const* d_in, const int* in_sizes, int n_in,
                              void* d_out, int out_size, void* d_ws, size_t ws_size,
                              hipStream_t stream) {
  (void)in_sizes; (void)n_in; (void)ws_size;
  const float* x    = (const float*)d_in[0];
  const float* gate = (const float*)d_in[1];
  const float* W1   = (const float*)d_in[2];
  const float* b1   = (const float*)d_in[3];
  const float* W2   = (const float*)d_in[4];
  const float* b2   = (const float*)d_in[5];
  float* out = (float*)d_out;

  char* p = (char*)d_ws;
  unsigned short* xb   = (unsigned short*)p; p += (size_t)TOKENS * D_ * 2;
  unsigned short* w1t  = (unsigned short*)p; p += (size_t)E_ * H_ * D_ * 2;
  unsigned short* w2t  = (unsigned short*)p; p += (size_t)E_ * D_ * H_ * 2;
  unsigned short* hbuf = (unsigned short*)p; p += (size_t)HPAD_ROWS * H_ * 2;
  int*   tok  = (int*)p;   p += (size_t)RROWS * 4;
  float* rw   = (float*)p; p += (size_t)RROWS * 4;
  int*   sel  = (int*)p;   p += (size_t)TOKENS * 2 * 4;
  float* wsel = (float*)p; p += (size_t)TOKENS * 2 * 4;
  int* cnt    = (int*)p;   p += 32 * 4;
  int* off    = (int*)p;   p += 32 * 4;
  int* cursor = (int*)p;   p += 32 * 4;

  hipMemsetAsync(cnt, 0, 32 * 4, stream);
  hipMemsetAsync(out, 0, (size_t)out_size * 4, stream);

  cvt_bf16_kernel<<<2048, 256, 0, stream>>>(x, xb, TOKENS * D_ / 4);
  transpose_cvt_kernel<<<E_ * (D_ / 64) * (H_ / 64), 256, 0, stream>>>(W1, w1t, D_, H_);
  transpose_cvt_kernel<<<E_ * (H_ / 64) * (D_ / 64), 256, 0, stream>>>(W2, w2t, H_, D_);
  gating_kernel<<<TOKENS / 4, 256, 0, stream>>>(x, gate, sel, wsel, cnt);
  scan_kernel<<<1, 64, 0, stream>>>(cnt, off, cursor);
  scatter_kernel<<<TOKENS / 256, 256, 0, stream>>>(sel, wsel, cursor, tok, rw);
  gemm1_kernel<<<E_ * 64 * 16, 256, 0, stream>>>(xb, w1t, b1, hbuf, tok, cnt, off);
  gemm2_kernel<<<E_ * 64 * 8, 256, 0, stream>>>(hbuf, w2t, b2, out, tok, rw, cnt, off);
}

// Round 2
// 622.727 us; speedup vs baseline: 1.0334x; 1.0334x over previous
//
#include <hip/hip_runtime.h>

#define E_      8
#define D_      1024
#define H_      2048
#define TOKENS  8192
#define RROWS   16384            // routed rows total (= TOKENS * TOP_K), exact
#define HPAD_ROWS (RROWS + 128)  // pad so GEMM2 A-staging over-read stays in bounds

using bf16x8 = __attribute__((ext_vector_type(8))) __bf16;
using f32x4  = __attribute__((ext_vector_type(4))) float;

__device__ __forceinline__ unsigned short f2bf(float f) {
  unsigned u = __builtin_bit_cast(unsigned, f);
  u += 0x7fffu + ((u >> 16) & 1u);   // RNE
  return (unsigned short)(u >> 16);
}

// async global->LDS, 16B per lane; LDS dest is wave-uniform base + lane*16
#define GLDS16(g, l) __builtin_amdgcn_global_load_lds( \
    (const __attribute__((address_space(1))) unsigned int*)(g), \
    (__attribute__((address_space(3))) unsigned int*)(l), 16, 0, 0)

// ---------------- prologue kernels ----------------

// src: [E][R][C] fp32  ->  dst: [E][C][R] bf16
__global__ void transpose_cvt_kernel(const float* __restrict__ src,
                                     unsigned short* __restrict__ dst,
                                     int R, int C) {
  int tilesC = C >> 6, tilesR = R >> 6;
  int per = tilesR * tilesC;
  int b = blockIdx.x;
  int e = b / per, rem = b % per;
  int rb = rem / tilesC, cb = rem % tilesC;
  __shared__ float tile[64][65];
  const float* s = src + (size_t)e * R * C;
  unsigned short* d = dst + (size_t)e * R * C;
  int r0 = rb << 6, c0 = cb << 6;
#pragma unroll
  for (int i = 0; i < 16; i++) {
    int idx = threadIdx.x + i * 256;
    int lr = idx >> 6, lc = idx & 63;
    tile[lr][lc] = s[(size_t)(r0 + lr) * C + (c0 + lc)];
  }
  __syncthreads();
#pragma unroll
  for (int i = 0; i < 16; i++) {
    int idx = threadIdx.x + i * 256;
    int lr = idx >> 6, lc = idx & 63;
    d[(size_t)(c0 + lr) * R + (r0 + lc)] = f2bf(tile[lc][lr]);
  }
}

// gating + x -> bf16 conversion fused (both consume the full x read)
__global__ void gating_kernel(const float* __restrict__ x, const float* __restrict__ gate,
                              unsigned short* __restrict__ xb,
                              int* __restrict__ sel, float* __restrict__ wsel,
                              int* __restrict__ cnt) {
  int lane = threadIdx.x & 63, wid = threadIdx.x >> 6;
  int t = (blockIdx.x << 2) + wid;          // one wave per token
  const float* xr = x + (size_t)t * D_;
  unsigned short* xbr = xb + (size_t)t * D_;
  float acc[8];
#pragma unroll
  for (int e = 0; e < 8; e++) acc[e] = 0.f;
  for (int i = 0; i < D_ / 64; i++) {
    int dd = (i << 6) + lane;
    float xv = xr[dd];
    xbr[dd] = f2bf(xv);
    const float4* g4 = reinterpret_cast<const float4*>(gate + dd * 8);
    float4 ga = g4[0], gb = g4[1];
    acc[0] += xv * ga.x; acc[1] += xv * ga.y; acc[2] += xv * ga.z; acc[3] += xv * ga.w;
    acc[4] += xv * gb.x; acc[5] += xv * gb.y; acc[6] += xv * gb.z; acc[7] += xv * gb.w;
  }
#pragma unroll
  for (int e = 0; e < 8; e++) {
#pragma unroll
    for (int off = 32; off; off >>= 1) acc[e] += __shfl_xor(acc[e], off);
  }
  if (lane == 0) {
    int i0 = 0; float v0 = acc[0];
#pragma unroll
    for (int e = 1; e < 8; e++) if (acc[e] > v0) { v0 = acc[e]; i0 = e; }
    int i1 = -1; float v1 = -3.4e38f;
#pragma unroll
    for (int e = 0; e < 8; e++) if (e != i0 && acc[e] > v1) { v1 = acc[e]; i1 = e; }
    // top-2-of-softmax renormalized: w0 = p0/(p0+p1) with p = exp(l - l_max)
    float p1 = expf(v1 - v0);
    float inv = 1.f / (1.f + p1);
    sel[t * 2] = i0; sel[t * 2 + 1] = i1;
    wsel[t * 2] = inv; wsel[t * 2 + 1] = p1 * inv;
    atomicAdd(&cnt[i0], 1);
    atomicAdd(&cnt[i1], 1);
  }
}

__global__ void scan_kernel(const int* __restrict__ cnt, int* __restrict__ off,
                            int* __restrict__ cursor) {
  if (threadIdx.x == 0) {
    int a = 0;
    for (int e = 0; e < 8; e++) { off[e] = a; cursor[e] = a; a += cnt[e]; }
  }
}

__global__ void scatter_kernel(const int* __restrict__ sel, const float* __restrict__ wsel,
                               int* __restrict__ cursor, int* __restrict__ tok_id,
                               float* __restrict__ rw) {
  int t = blockIdx.x * blockDim.x + threadIdx.x;
  if (t >= TOKENS) return;
  int e0 = sel[t * 2], e1 = sel[t * 2 + 1];
  int p0 = atomicAdd(&cursor[e0], 1);
  tok_id[p0] = t; rw[p0] = wsel[t * 2];
  int p1 = atomicAdd(&cursor[e1], 1);
  tok_id[p1] = t; rw[p1] = wsel[t * 2 + 1];
}

// ---------------- grouped GEMMs ----------------
// 128x128 tile, BK=64, 4 waves (2x2), 16x16x32 bf16 MFMA.
// LDS: [128 rows][64 k] bf16, XOR-swizzled 16B chunks (chunk^(row&7)), swizzle
// folded into the per-lane GLOBAL source address (LDS dest stays linear).
// 2-phase double-buffered pipeline (T3 minimum): issue next-tile
// global_load_lds BEFORE computing the current tile; one vmcnt(0)+barrier per
// K-step. XCD-chunked block swizzle: one expert == one XCD chunk, so the
// expert's whole B panel (4 MB) stays resident in that XCD's L2.

__global__ __launch_bounds__(256) void gemm1_kernel(
    const unsigned short* __restrict__ xb,    // [TOKENS][D_] bf16
    const unsigned short* __restrict__ w1t,   // [E][H][D] bf16 (k=d contiguous)
    const float* __restrict__ b1,             // [E][H]
    unsigned short* __restrict__ hbuf,        // [HPAD_ROWS][H_] bf16
    const int* __restrict__ tok_id,
    const int* __restrict__ cnt, const int* __restrict__ off) {
  const int nwg = E_ * 64 * 16;
  const int raw = blockIdx.x;
  const int bid = (raw & 7) * (nwg >> 3) + (raw >> 3);   // XCD-chunked swizzle
  const int e  = bid >> 10;          // 64 rb * 16 cb
  const int rb = (bid >> 4) & 63;
  const int cb = bid & 15;
  const int rows = cnt[e];
  const int m0 = rb << 7;
  if (m0 >= rows) return;
  const int base = off[e];
  const int tid = threadIdx.x, lane = tid & 63, wid = tid >> 6;
  const int wr = wid >> 1, wc = wid & 1;

  __shared__ __align__(16) unsigned short Asm[2][128 * 64];
  __shared__ __align__(16) unsigned short Bsm[2][128 * 64];
  __shared__ int toksm[128];

  if (tid < 128) {
    int r = m0 + tid;
    if (r >= rows) r = rows - 1;     // clamp: garbage rows computed, never stored
    toksm[tid] = tok_id[base + r];
  }
  __syncthreads();

  const int c8 = lane & 7, r8 = lane >> 3;
  const size_t swz = (size_t)((c8 ^ r8) << 4);
  size_t gA[4], gB[4];
  const int n0 = cb << 7;
#pragma unroll
  for (int i = 0; i < 4; i++) {
    int r = ((wid << 2) + i) << 3;   // 8-row group base
    gA[i] = (size_t)toksm[r + r8] * (D_ * 2) + swz;
    gB[i] = (size_t)(n0 + r + r8) * (D_ * 2) + swz;
  }
  const char* Ab = (const char*)xb;
  const char* Bb = (const char*)w1t + (size_t)e * H_ * D_ * 2;

  f32x4 acc[4][4] = {};
  const int NK = D_ / 64;   // 16

  // prologue: stage tile 0 into buffer 0
#pragma unroll
  for (int i = 0; i < 4; i++) GLDS16(Ab + gA[i], &Asm[0][((wid << 2) + i) << 9]);
#pragma unroll
  for (int i = 0; i < 4; i++) GLDS16(Bb + gB[i], &Bsm[0][((wid << 2) + i) << 9]);
  asm volatile("s_waitcnt vmcnt(0)" ::: "memory");
  __syncthreads();

  for (int t = 0; t < NK; ++t) {
    const int cur = t & 1;
    if (t + 1 < NK) {
      const int nxt = cur ^ 1;
      const size_t koff = (size_t)(t + 1) << 7;   // 64 cols * 2B
#pragma unroll
      for (int i = 0; i < 4; i++) GLDS16(Ab + gA[i] + koff, &Asm[nxt][((wid << 2) + i) << 9]);
#pragma unroll
      for (int i = 0; i < 4; i++) GLDS16(Bb + gB[i] + koff, &Bsm[nxt][((wid << 2) + i) << 9]);
    }
#pragma unroll
    for (int kk = 0; kk < 2; kk++) {
      const int cby = (((kk << 2) + (lane >> 4)) ^ (lane & 7)) << 4;
      bf16x8 a[4], b[4];
      const char* Ap = (const char*)Asm[cur] + ((wr << 6) + (lane & 15)) * 128 + cby;
      const char* Bp = (const char*)Bsm[cur] + ((wc << 6) + (lane & 15)) * 128 + cby;
#pragma unroll
      for (int mi = 0; mi < 4; mi++) a[mi] = *(const bf16x8*)(Ap + mi * 2048);
#pragma unroll
      for (int ni = 0; ni < 4; ni++) b[ni] = *(const bf16x8*)(Bp + ni * 2048);
#pragma unroll
      for (int mi = 0; mi < 4; mi++)
#pragma unroll
        for (int ni = 0; ni < 4; ni++)
          acc[mi][ni] = __builtin_amdgcn_mfma_f32_16x16x32_bf16(a[mi], b[ni], acc[mi][ni], 0, 0, 0);
    }
    asm volatile("s_waitcnt vmcnt(0)" ::: "memory");
    __syncthreads();
  }

  const int rcnt = rows - m0;
  const float* b1e = b1 + e * H_;
#pragma unroll
  for (int mi = 0; mi < 4; mi++) {
#pragma unroll
    for (int q = 0; q < 4; q++) {
      int rl = (wr << 6) + (mi << 4) + ((lane >> 4) << 2) + q;
      if (rl < rcnt) {
        unsigned short* hrow = hbuf + (size_t)(base + m0 + rl) * H_;
#pragma unroll
        for (int ni = 0; ni < 4; ni++) {
          int ncol = n0 + (wc << 6) + (ni << 4) + (lane & 15);
          float v = acc[mi][ni][q] + b1e[ncol];
          hrow[ncol] = f2bf(fmaxf(v, 0.f));
        }
      }
    }
  }
}

__global__ __launch_bounds__(256) void gemm2_kernel(
    const unsigned short* __restrict__ hbuf,  // [HPAD_ROWS][H_] bf16
    const unsigned short* __restrict__ w2t,   // [E][D][H] bf16 (k=h contiguous)
    const float* __restrict__ b2,             // [E][D]
    float* __restrict__ out,                  // [TOKENS][D_] fp32 (zeroed)
    const int* __restrict__ tok_id, const float* __restrict__ rw,
    const int* __restrict__ cnt, const int* __restrict__ off) {
  const int nwg = E_ * 64 * 8;
  const int raw = blockIdx.x;
  const int bid = (raw & 7) * (nwg >> 3) + (raw >> 3);   // XCD-chunked swizzle
  const int e  = bid >> 9;           // 64 rb * 8 cb
  const int rb = (bid >> 3) & 63;
  const int cb = bid & 7;
  const int rows = cnt[e];
  const int m0 = rb << 7;
  if (m0 >= rows) return;
  const int base = off[e];
  const int tid = threadIdx.x, lane = tid & 63, wid = tid >> 6;
  const int wr = wid >> 1, wc = wid & 1;

  __shared__ __align__(16) unsigned short Asm[2][128 * 64];
  __shared__ __align__(16) unsigned short Bsm[2][128 * 64];

  const int c8 = lane & 7, r8 = lane >> 3;
  const size_t swz = (size_t)((c8 ^ r8) << 4);
  size_t gA[4], gB[4];
  const int n0 = cb << 7;
#pragma unroll
  for (int i = 0; i < 4; i++) {
    int r = ((wid << 2) + i) << 3;
    gA[i] = (size_t)(base + m0 + r + r8) * (H_ * 2) + swz;  // contiguous routed rows
    gB[i] = (size_t)(n0 + r + r8) * (H_ * 2) + swz;
  }
  const char* Ab = (const char*)hbuf;
  const char* Bb = (const char*)w2t + (size_t)e * D_ * H_ * 2;

  f32x4 acc[4][4] = {};
  const int NK = H_ / 64;   // 32

#pragma unroll
  for (int i = 0; i < 4; i++) GLDS16(Ab + gA[i], &Asm[0][((wid << 2) + i) << 9]);
#pragma unroll
  for (int i = 0; i < 4; i++) GLDS16(Bb + gB[i], &Bsm[0][((wid << 2) + i) << 9]);
  asm volatile("s_waitcnt vmcnt(0)" ::: "memory");
  __syncthreads();

  for (int t = 0; t < NK; ++t) {
    const int cur = t & 1;
    if (t + 1 < NK) {
      const int nxt = cur ^ 1;
      const size_t koff = (size_t)(t + 1) << 7;
#pragma unroll
      for (int i = 0; i < 4; i++) GLDS16(Ab + gA[i] + koff, &Asm[nxt][((wid << 2) + i) << 9]);
#pragma unroll
      for (int i = 0; i < 4; i++) GLDS16(Bb + gB[i] + koff, &Bsm[nxt][((wid << 2) + i) << 9]);
    }
#pragma unroll
    for (int kk = 0; kk < 2; kk++) {
      const int cby = (((kk << 2) + (lane >> 4)) ^ (lane & 7)) << 4;
      bf16x8 a[4], b[4];
      const char* Ap = (const char*)Asm[cur] + ((wr << 6) + (lane & 15)) * 128 + cby;
      const char* Bp = (const char*)Bsm[cur] + ((wc << 6) + (lane & 15)) * 128 + cby;
#pragma unroll
      for (int mi = 0; mi < 4; mi++) a[mi] = *(const bf16x8*)(Ap + mi * 2048);
#pragma unroll
      for (int ni = 0; ni < 4; ni++) b[ni] = *(const bf16x8*)(Bp + ni * 2048);
#pragma unroll
      for (int mi = 0; mi < 4; mi++)
#pragma unroll
        for (int ni = 0; ni < 4; ni++)
          acc[mi][ni] = __builtin_amdgcn_mfma_f32_16x16x32_bf16(a[mi], b[ni], acc[mi][ni], 0, 0, 0);
    }
    asm volatile("s_waitcnt vmcnt(0)" ::: "memory");
    __syncthreads();
  }

  const int rcnt = rows - m0;
  const float* b2e = b2 + e * D_;
#pragma unroll
  for (int mi = 0; mi < 4; mi++) {
#pragma unroll
    for (int q = 0; q < 4; q++) {
      int rl = (wr << 6) + (mi << 4) + ((lane >> 4) << 2) + q;
      if (rl < rcnt) {
        int R = base + m0 + rl;
        float w = rw[R];
        int t = tok_id[R];
        float* orow = out + (size_t)t * D_;
#pragma unroll
        for (int ni = 0; ni < 4; ni++) {
          int ncol = n0 + (wc << 6) + (ni << 4) + (lane & 15);
          atomicAdd(&orow[ncol], w * (acc[mi][ni][q] + b2e[ncol]));
        }
      }
    }
  }
}

// ---------------- launcher ----------------

extern "C" void kernel_launch(void* const* d_in, const int* in_sizes, int n_in,
                              void* d_out, int out_size, void* d_ws, size_t ws_size,
                              hipStream_t stream) {
  (void)in_sizes; (void)n_in; (void)ws_size;
  const float* x    = (const float*)d_in[0];
  const float* gate = (const float*)d_in[1];
  const float* W1   = (const float*)d_in[2];
  const float* b1   = (const float*)d_in[3];
  const float* W2   = (const float*)d_in[4];
  const float* b2   = (const float*)d_in[5];
  float* out = (float*)d_out;

  char* p = (char*)d_ws;
  unsigned short* xb   = (unsigned short*)p; p += (size_t)TOKENS * D_ * 2;
  unsigned short* w1t  = (unsigned short*)p; p += (size_t)E_ * H_ * D_ * 2;
  unsigned short* w2t  = (unsigned short*)p; p += (size_t)E_ * D_ * H_ * 2;
  unsigned short* hbuf = (unsigned short*)p; p += (size_t)HPAD_ROWS * H_ * 2;
  int*   tok  = (int*)p;   p += (size_t)RROWS * 4;
  float* rw   = (float*)p; p += (size_t)RROWS * 4;
  int*   sel  = (int*)p;   p += (size_t)TOKENS * 2 * 4;
  float* wsel = (float*)p; p += (size_t)TOKENS * 2 * 4;
  int* cnt    = (int*)p;   p += 32 * 4;
  int* off    = (int*)p;   p += 32 * 4;
  int* cursor = (int*)p;   p += 32 * 4;

  hipMemsetAsync(cnt, 0, 32 * 4, stream);
  hipMemsetAsync(out, 0, (size_t)out_size * 4, stream);

  transpose_cvt_kernel<<<E_ * (D_ / 64) * (H_ / 64), 256, 0, stream>>>(W1, w1t, D_, H_);
  transpose_cvt_kernel<<<E_ * (H_ / 64) * (D_ / 64), 256, 0, stream>>>(W2, w2t, H_, D_);
  gating_kernel<<<TOKENS / 4, 256, 0, stream>>>(x, gate, xb, sel, wsel, cnt);
  scan_kernel<<<1, 64, 0, stream>>>(cnt, off, cursor);
  scatter_kernel<<<TOKENS / 256, 256, 0, stream>>>(sel, wsel, cursor, tok, rw);
  gemm1_kernel<<<E_ * 64 * 16, 256, 0, stream>>>(xb, w1t, b1, hbuf, tok, cnt, off);
  gemm2_kernel<<<E_ * 64 * 8, 256, 0, stream>>>(hbuf, w2t, b2, out, tok, rw, cnt, off);
}